// Round 1
// baseline (54325.818 us; speedup 1.0000x reference)
//
#include <hip/hip_runtime.h>

#define DD 512
#define KK 8

__device__ __forceinline__ float sigmoidf_(float x) {
    return 1.0f / (1.0f + __expf(-x));
}

// ---------------- Leaf pass: c = sigmoid(i) * tanh(g), h0=c0=0 ----------------
// Only gate rows [0,512) (i) and [1024,1536) (g) of W_ih are needed.
template<int LPB>
__global__ __launch_bounds__(256)
void leaf_kernel(const float* __restrict__ emb,
                 const float* __restrict__ W_ih,
                 const float* __restrict__ b_ih,
                 const float* __restrict__ b_hh,
                 float* __restrict__ z_out,
                 int leaf_base)
{
    __shared__ float xs[LPB][DD];
    const int b0 = blockIdx.x * LPB;
    const int tid = threadIdx.x;

    for (int s = 0; s < LPB; ++s)
        for (int d = tid; d < DD; d += 256)
            xs[s][d] = emb[(size_t)(leaf_base + b0 + s) * DD + d];
    __syncthreads();

    #pragma unroll
    for (int jj = 0; jj < 2; ++jj) {
        const int j = tid + jj * 256;
        const float* wi = W_ih + (size_t)j * DD;             // i-gate row
        const float* wg = W_ih + (size_t)(j + 2 * DD) * DD;  // g-gate row
        float ai[LPB], ag[LPB];
        const float bi = b_ih[j] + b_hh[j];
        const float bg = b_ih[j + 2 * DD] + b_hh[j + 2 * DD];
        #pragma unroll
        for (int s = 0; s < LPB; ++s) { ai[s] = bi; ag[s] = bg; }
        for (int d = 0; d < DD; ++d) {
            const float w0 = wi[d], w1 = wg[d];
            #pragma unroll
            for (int s = 0; s < LPB; ++s) {
                const float x = xs[s][d];
                ai[s] = fmaf(w0, x, ai[s]);
                ag[s] = fmaf(w1, x, ag[s]);
            }
        }
        #pragma unroll
        for (int s = 0; s < LPB; ++s)
            z_out[(size_t)(b0 + s) * DD + j] = sigmoidf_(ai[s]) * tanhf(ag[s]);
    }
}

// ---------------- Per-level kernel: child transform + 9-step LSTM ----------------
// Block handles SPB sequences in lockstep. h, x_t, child-z staged in LDS
// (broadcast reads); gate accumulators + c-state in registers. Each W element
// loaded once feeds SPB FMAs.
template<int SPB>
__global__ __launch_bounds__(256)
void lstm_kernel(const float* __restrict__ emb,
                 const int*   __restrict__ dep,
                 const float* __restrict__ W_dep,
                 const float* __restrict__ b_dep,
                 const float* __restrict__ W_ih,
                 const float* __restrict__ W_hh,
                 const float* __restrict__ b_ih,
                 const float* __restrict__ b_hh,
                 const float* __restrict__ z_in,
                 float* __restrict__ z_out,
                 int node_base, int child_base)
{
    __shared__ float hs[SPB][DD];
    __shared__ float xs[SPB][DD];
    __shared__ float zs[SPB][DD];
    const int b0 = blockIdx.x * SPB;
    const int tid = threadIdx.x;

    for (int s = 0; s < SPB; ++s)
        for (int d = tid; d < DD; d += 256)
            hs[s][d] = 0.0f;

    float creg[2][SPB];
    #pragma unroll
    for (int jj = 0; jj < 2; ++jj)
        #pragma unroll
        for (int s = 0; s < SPB; ++s) creg[jj][s] = 0.0f;

    for (int t = 0; t < KK + 1; ++t) {
        // ---- build x_t in LDS ----
        if (t < KK) {
            for (int s = 0; s < SPB; ++s)
                for (int d = tid; d < DD; d += 256)
                    zs[s][d] = z_in[((size_t)(b0 + s) * KK + t) * DD + d];
            int pp[SPB];
            #pragma unroll
            for (int s = 0; s < SPB; ++s)
                pp[s] = dep[child_base + (b0 + s) * KK + t];
            __syncthreads();
            // zc = W_dep[p] @ z_child + b_dep[p]
            #pragma unroll
            for (int jj = 0; jj < 2; ++jj) {
                const int j = tid + jj * 256;
                float acc[SPB];
                const float* wr[SPB];
                #pragma unroll
                for (int s = 0; s < SPB; ++s) {
                    wr[s]  = W_dep + ((size_t)pp[s] * DD + j) * DD;
                    acc[s] = b_dep[pp[s] * DD + j];
                }
                for (int d = 0; d < DD; ++d) {
                    #pragma unroll
                    for (int s = 0; s < SPB; ++s)
                        acc[s] = fmaf(wr[s][d], zs[s][d], acc[s]);
                }
                #pragma unroll
                for (int s = 0; s < SPB; ++s)
                    xs[s][j] = acc[s];
            }
        } else {
            for (int s = 0; s < SPB; ++s)
                for (int d = tid; d < DD; d += 256)
                    xs[s][d] = emb[(size_t)(node_base + b0 + s) * DD + d];
        }
        __syncthreads();

        // ---- gates: thread owns element j = tid, tid+256; all 4 gate rows ----
        float nh[2][SPB];
        #pragma unroll
        for (int jj = 0; jj < 2; ++jj) {
            const int j = tid + jj * 256;
            float ai[SPB], af[SPB], ag[SPB], ao[SPB];
            const float bi = b_ih[j]          + b_hh[j];
            const float bf = b_ih[j + DD]     + b_hh[j + DD];
            const float bg = b_ih[j + 2 * DD] + b_hh[j + 2 * DD];
            const float bo = b_ih[j + 3 * DD] + b_hh[j + 3 * DD];
            #pragma unroll
            for (int s = 0; s < SPB; ++s) { ai[s]=bi; af[s]=bf; ag[s]=bg; ao[s]=bo; }
            const float* wi = W_ih + (size_t)j * DD;
            const float* wf = wi + (size_t)DD * DD;
            const float* wg = wf + (size_t)DD * DD;
            const float* wo = wg + (size_t)DD * DD;
            const float* ui = W_hh + (size_t)j * DD;
            const float* uf = ui + (size_t)DD * DD;
            const float* ug = uf + (size_t)DD * DD;
            const float* uo = ug + (size_t)DD * DD;
            for (int d = 0; d < DD; ++d) {
                const float w0 = wi[d], w1 = wf[d], w2 = wg[d], w3 = wo[d];
                const float u0 = ui[d], u1 = uf[d], u2 = ug[d], u3 = uo[d];
                #pragma unroll
                for (int s = 0; s < SPB; ++s) {
                    const float x = xs[s][d];
                    const float h = hs[s][d];
                    ai[s] = fmaf(w0, x, fmaf(u0, h, ai[s]));
                    af[s] = fmaf(w1, x, fmaf(u1, h, af[s]));
                    ag[s] = fmaf(w2, x, fmaf(u2, h, ag[s]));
                    ao[s] = fmaf(w3, x, fmaf(u3, h, ao[s]));
                }
            }
            #pragma unroll
            for (int s = 0; s < SPB; ++s) {
                const float i_ = sigmoidf_(ai[s]);
                const float f_ = sigmoidf_(af[s]);
                const float g_ = tanhf(ag[s]);
                const float o_ = sigmoidf_(ao[s]);
                const float c  = fmaf(f_, creg[jj][s], i_ * g_);
                creg[jj][s] = c;
                nh[jj][s] = o_ * tanhf(c);
            }
        }
        __syncthreads();   // all reads of hs done
        #pragma unroll
        for (int jj = 0; jj < 2; ++jj)
            #pragma unroll
            for (int s = 0; s < SPB; ++s)
                hs[s][tid + jj * 256] = nh[jj][s];
        __syncthreads();   // new h visible
    }

    #pragma unroll
    for (int jj = 0; jj < 2; ++jj)
        #pragma unroll
        for (int s = 0; s < SPB; ++s)
            z_out[(size_t)(b0 + s) * DD + tid + jj * 256] = creg[jj][s];
}

// OFF = {0, 1, 9, 73, 585, 4681, 37449}
extern "C" void kernel_launch(void* const* d_in, const int* in_sizes, int n_in,
                              void* d_out, int out_size, void* d_ws, size_t ws_size,
                              hipStream_t stream)
{
    (void)in_sizes; (void)n_in; (void)out_size; (void)ws_size;
    const float* emb   = (const float*)d_in[0];
    const int*   dep   = (const int*)  d_in[1];
    const float* W_dep = (const float*)d_in[2];
    const float* b_dep = (const float*)d_in[3];
    const float* W_ih  = (const float*)d_in[4];
    const float* W_hh  = (const float*)d_in[5];
    const float* b_ih  = (const float*)d_in[6];
    const float* b_hh  = (const float*)d_in[7];
    float* out = (float*)d_out;

    float* zA = (float*)d_ws;                 // up to 32768*512 floats (64 MB)
    float* zB = zA + (size_t)32768 * DD;      // up to 4096*512 floats (8 MB)

    // Leaf level: 32768 leaves -> zA
    leaf_kernel<8><<<4096, 256, 0, stream>>>(emb, W_ih, b_ih, b_hh, zA, 4681);

    // level 4: m=4096, nodes [585,4681), children [4681,37449)
    lstm_kernel<8><<<512, 256, 0, stream>>>(emb, dep, W_dep, b_dep, W_ih, W_hh,
                                            b_ih, b_hh, zA, zB, 585, 4681);
    // level 3: m=512, nodes [73,585), children [585,4681)
    lstm_kernel<4><<<128, 256, 0, stream>>>(emb, dep, W_dep, b_dep, W_ih, W_hh,
                                            b_ih, b_hh, zB, zA, 73, 585);
    // level 2: m=64, nodes [9,73), children [73,585)
    lstm_kernel<2><<<32, 256, 0, stream>>>(emb, dep, W_dep, b_dep, W_ih, W_hh,
                                           b_ih, b_hh, zA, zB, 9, 73);
    // level 1: m=8, nodes [1,9), children [9,73)
    lstm_kernel<1><<<8, 256, 0, stream>>>(emb, dep, W_dep, b_dep, W_ih, W_hh,
                                          b_ih, b_hh, zB, zA, 1, 9);
    // level 0: m=1, node [0,1), children [1,9)  -> final c to d_out
    lstm_kernel<1><<<1, 256, 0, stream>>>(emb, dep, W_dep, b_dep, W_ih, W_hh,
                                          b_ih, b_hh, zA, out, 0, 1);
}

// Round 2
// 2707.898 us; speedup vs baseline: 20.0620x; 20.0620x over previous
//
#include <hip/hip_runtime.h>

typedef __attribute__((ext_vector_type(8))) short short8;
typedef __attribute__((ext_vector_type(4))) float f32x4;

#define OFF5 4681

__device__ __forceinline__ unsigned short f2bf(float x){
  union { float f; unsigned u; } v; v.f = x;
  unsigned r = v.u + 0x7fffu + ((v.u >> 16) & 1u);
  return (unsigned short)(r >> 16);
}
__device__ __forceinline__ float sigm(float x){ return 1.0f / (1.0f + __expf(-x)); }

__device__ __forceinline__ short8 load_bf8_f32(const float* p){
  float4 a = *(const float4*)p;
  float4 b = *(const float4*)(p + 4);
  short8 r;
  r[0]=(short)f2bf(a.x); r[1]=(short)f2bf(a.y); r[2]=(short)f2bf(a.z); r[3]=(short)f2bf(a.w);
  r[4]=(short)f2bf(b.x); r[5]=(short)f2bf(b.y); r[6]=(short)f2bf(b.z); r[7]=(short)f2bf(b.w);
  return r;
}

__device__ __forceinline__ f32x4 mfma16(short8 a, short8 b, f32x4 c){
  return __builtin_amdgcn_mfma_f32_16x16x32_bf16(a, b, c, 0, 0, 0);
}

// ---------- fp32 -> bf16 convert ----------
__global__ __launch_bounds__(256) void conv_kernel(const float* __restrict__ in,
                                                   unsigned short* __restrict__ out, int n8){
  for (int i = blockIdx.x * 256 + threadIdx.x; i < n8; i += gridDim.x * 256){
    short8 v = load_bf8_f32(in + (size_t)i * 8);
    *(short8*)(out + (size_t)i * 8) = v;
  }
}

// ---------- leaf: z = sigmoid(x@Wi^T + bi) * tanh(x@Wg^T + bg) ----------
// wave = 64 rows x 16 cols; grid = 4096 blocks x 4 waves = 512 rb x 32 cb
__global__ __launch_bounds__(256) void leaf_mfma(
    const float* __restrict__ emb, const unsigned short* __restrict__ Wihb,
    const float* __restrict__ b_ih, const float* __restrict__ b_hh,
    unsigned short* __restrict__ zout)
{
  const int lane = threadIdx.x & 63, w = threadIdx.x >> 6;
  const int flat = blockIdx.x * 4 + w;
  const int rb = flat >> 5, cb = flat & 31;
  const int r15 = lane & 15, g4 = lane >> 4;

  const float* arow[4];
  #pragma unroll
  for (int mi = 0; mi < 4; ++mi)
    arow[mi] = emb + ((size_t)(OFF5 + rb*64 + mi*16 + r15)) * 512 + g4*8;
  const unsigned short* bi = Wihb + ((size_t)(cb*16 + r15)) * 512 + g4*8;
  const unsigned short* bg = Wihb + ((size_t)(1024 + cb*16 + r15)) * 512 + g4*8;

  f32x4 ai[4] = {}, ag[4] = {};
  for (int ks = 0; ks < 16; ++ks){
    short8 vb0 = *(const short8*)(bi + ks*32);
    short8 vb1 = *(const short8*)(bg + ks*32);
    #pragma unroll
    for (int mi = 0; mi < 4; ++mi){
      short8 a = load_bf8_f32(arow[mi] + ks*32);
      ai[mi] = mfma16(a, vb0, ai[mi]);
      ag[mi] = mfma16(a, vb1, ag[mi]);
    }
  }
  const int col = cb*16 + r15;
  const float bbi = b_ih[col] + b_hh[col];
  const float bbg = b_ih[1024 + col] + b_hh[1024 + col];
  #pragma unroll
  for (int mi = 0; mi < 4; ++mi)
    #pragma unroll
    for (int j = 0; j < 4; ++j){
      int row = rb*64 + mi*16 + g4*4 + j;
      float z = sigm(ai[mi][j] + bbi) * tanhf(ag[mi][j] + bbg);
      zout[(size_t)row * 512 + col] = f2bf(z);
    }
}

// ---------- counting sort of children by dep type (padded 64-row tiles) ----------
__global__ __launch_bounds__(256) void sort_kernel(const int* __restrict__ dep, int child_base, int mk,
                                                   int* __restrict__ perm, int* __restrict__ tile_p,
                                                   int* __restrict__ meta){
  __shared__ int cnt[8], poff[8], fill[8], ntot_s;
  const int tid = threadIdx.x;
  if (tid < 8){ cnt[tid] = 0; fill[tid] = 0; }
  __syncthreads();
  for (int i = tid; i < mk; i += 256) atomicAdd(&cnt[dep[child_base + i]], 1);
  __syncthreads();
  if (tid == 0){
    int t = 0;
    for (int p = 0; p < 8; ++p){
      poff[p] = t * 64;
      int nt = (cnt[p] + 63) >> 6;
      for (int q = 0; q < nt; ++q) tile_p[t + q] = p;
      t += nt;
    }
    ntot_s = t; meta[0] = t;
  }
  __syncthreads();
  const int tot = ntot_s * 64;
  for (int i = tid; i < tot; i += 256) perm[i] = -1;
  __syncthreads();
  for (int i = tid; i < mk; i += 256){
    int p = dep[child_base + i];
    int pos = poff[p] + atomicAdd(&fill[p], 1);
    perm[pos] = i;
  }
}

// ---------- grouped child transform: zc = z @ Wdep[p]^T + b_dep[p] -> seq ----------
// block: 64 rows (one padded tile, uniform p) x 64 cols; wave = 64x16
__global__ __launch_bounds__(256) void childx_mfma(
    const unsigned short* __restrict__ zin, const unsigned short* __restrict__ Wdepb,
    const float* __restrict__ b_dep, const int* __restrict__ perm,
    const int* __restrict__ tile_p, const int* __restrict__ meta,
    unsigned short* __restrict__ seq)
{
  const int bid = blockIdx.x, mt = bid >> 3, nb = bid & 7;
  if (mt >= meta[0]) return;
  const int p = tile_p[mt];
  const int lane = threadIdx.x & 63, w = threadIdx.x >> 6;
  const int r15 = lane & 15, g4 = lane >> 4;
  const int colc = nb*64 + w*16 + r15;

  const unsigned short* arow[4];
  #pragma unroll
  for (int mi = 0; mi < 4; ++mi){
    int c = perm[mt*64 + mi*16 + r15];
    arow[mi] = zin + (size_t)(c < 0 ? 0 : c) * 512 + g4*8;
  }
  const unsigned short* brow = Wdepb + ((size_t)p * 512 + colc) * 512 + g4*8;

  f32x4 acc[4] = {};
  for (int ks = 0; ks < 16; ++ks){
    short8 b = *(const short8*)(brow + ks*32);
    #pragma unroll
    for (int mi = 0; mi < 4; ++mi){
      short8 a = *(const short8*)(arow[mi] + ks*32);
      acc[mi] = mfma16(a, b, acc[mi]);
    }
  }
  const float bd = b_dep[p * 512 + colc];
  #pragma unroll
  for (int mi = 0; mi < 4; ++mi)
    #pragma unroll
    for (int j = 0; j < 4; ++j){
      int c = perm[mt*64 + mi*16 + g4*4 + j];
      if (c < 0) continue;
      int node = c >> 3, t = c & 7;
      seq[((size_t)node * 8 + t) * 512 + colc] = f2bf(acc[mi][j] + bd);
    }
}

// ---------- fused recurrent step: gates GEMM + LSTM pointwise ----------
// block: 64 rows x 16 gate-cols, wave w computes gate w. grid = ceil(m/64)*32
__global__ __launch_bounds__(256) void step_mfma(
    const unsigned short* __restrict__ xb, const float* __restrict__ xf, long xstride,
    const unsigned short* __restrict__ hin, unsigned short* __restrict__ hout,
    float* __restrict__ cbuf,
    const unsigned short* __restrict__ Wihb, const unsigned short* __restrict__ Whhb,
    const float* __restrict__ b_ih, const float* __restrict__ b_hh,
    int m, int first, int last,
    unsigned short* __restrict__ zout, float* __restrict__ fout)
{
  __shared__ float gl[4][64][16];
  const int bid = blockIdx.x, mb = bid >> 5, cb = bid & 31;
  const int tid = threadIdx.x, lane = tid & 63, w = tid >> 6;
  const int r15 = lane & 15, g4 = lane >> 4;
  const int r0 = mb * 64;
  const int brow = w * 512 + cb * 16 + r15;

  const unsigned short* bX = Wihb + (size_t)brow * 512 + g4*8;
  const unsigned short* bH = Whhb + (size_t)brow * 512 + g4*8;

  f32x4 acc[4] = {};
  if (xb){
    const unsigned short* ax[4];
    #pragma unroll
    for (int mi = 0; mi < 4; ++mi)
      ax[mi] = xb + (size_t)(r0 + mi*16 + r15) * xstride + g4*8;
    for (int ks = 0; ks < 16; ++ks){
      short8 b = *(const short8*)(bX + ks*32);
      #pragma unroll
      for (int mi = 0; mi < 4; ++mi){
        short8 a = *(const short8*)(ax[mi] + ks*32);
        acc[mi] = mfma16(a, b, acc[mi]);
      }
    }
  } else {
    const float* ax[4];
    #pragma unroll
    for (int mi = 0; mi < 4; ++mi)
      ax[mi] = xf + (size_t)(r0 + mi*16 + r15) * xstride + g4*8;
    for (int ks = 0; ks < 16; ++ks){
      short8 b = *(const short8*)(bX + ks*32);
      #pragma unroll
      for (int mi = 0; mi < 4; ++mi){
        short8 a = load_bf8_f32(ax[mi] + ks*32);
        acc[mi] = mfma16(a, b, acc[mi]);
      }
    }
  }
  if (!first){
    const unsigned short* ah[4];
    #pragma unroll
    for (int mi = 0; mi < 4; ++mi)
      ah[mi] = hin + (size_t)(r0 + mi*16 + r15) * 512 + g4*8;
    for (int ks = 0; ks < 16; ++ks){
      short8 b = *(const short8*)(bH + ks*32);
      #pragma unroll
      for (int mi = 0; mi < 4; ++mi){
        short8 a = *(const short8*)(ah[mi] + ks*32);
        acc[mi] = mfma16(a, b, acc[mi]);
      }
    }
  }

  #pragma unroll
  for (int mi = 0; mi < 4; ++mi)
    #pragma unroll
    for (int j = 0; j < 4; ++j)
      gl[w][mi*16 + g4*4 + j][r15] = acc[mi][j];
  __syncthreads();

  const int col0 = cb * 16;
  for (int e = tid; e < 1024; e += 256){
    int lr = e >> 4, cc = e & 15;
    int row = r0 + lr, gcol = col0 + cc;
    size_t idx = (size_t)row * 512 + gcol;
    float iv = sigm (gl[0][lr][cc] + b_ih[gcol]        + b_hh[gcol]);
    float fv = sigm (gl[1][lr][cc] + b_ih[512 + gcol]  + b_hh[512 + gcol]);
    float gv = tanhf(gl[2][lr][cc] + b_ih[1024 + gcol] + b_hh[1024 + gcol]);
    float ov = sigm (gl[3][lr][cc] + b_ih[1536 + gcol] + b_hh[1536 + gcol]);
    float cold = first ? 0.0f : cbuf[idx];
    float cnew = fv * cold + iv * gv;
    if (!last){
      cbuf[idx] = cnew;
      hout[idx] = f2bf(ov * tanhf(cnew));
    } else {
      if (zout) zout[idx] = f2bf(cnew);
      if (fout && row < m) fout[idx] = cnew;
    }
  }
}

// OFF = {0, 1, 9, 73, 585, 4681, 37449}
extern "C" void kernel_launch(void* const* d_in, const int* in_sizes, int n_in,
                              void* d_out, int out_size, void* d_ws, size_t ws_size,
                              hipStream_t stream)
{
  (void)in_sizes; (void)n_in; (void)out_size; (void)ws_size;
  const float* emb   = (const float*)d_in[0];
  const int*   dep   = (const int*)  d_in[1];
  const float* W_dep = (const float*)d_in[2];
  const float* b_dep = (const float*)d_in[3];
  const float* W_ih  = (const float*)d_in[4];
  const float* W_hh  = (const float*)d_in[5];
  const float* b_ih  = (const float*)d_in[6];
  const float* b_hh  = (const float*)d_in[7];
  float* out = (float*)d_out;

  // ws layout (bf16 elements unless noted); total ~92 MB
  unsigned short* Wihb  = (unsigned short*)d_ws;          // 2048*512
  unsigned short* Whhb  = Wihb  + (size_t)2048*512;       // 2048*512
  unsigned short* Wdepb = Whhb  + (size_t)2048*512;       // 8*512*512
  unsigned short* Z0    = Wdepb + (size_t)8*512*512;      // 32768*512
  unsigned short* Z1    = Z0    + (size_t)32768*512;      // 4096*512
  unsigned short* seq   = Z1    + (size_t)4096*512;       // 4096*8*512
  unsigned short* hA    = seq   + (size_t)4096*8*512;     // 4096*512
  unsigned short* hB    = hA    + (size_t)4096*512;       // 4096*512
  float* cbuf = (float*)(hB + (size_t)4096*512);          // 4096*512 fp32
  int* perm   = (int*)(cbuf + (size_t)4096*512);          // 33280
  int* tile_p = perm + 33280;                             // 520
  int* meta   = tile_p + 520;                             // 1

  conv_kernel<<<512,  256, 0, stream>>>(W_ih,  Wihb,  2048*512/8);
  conv_kernel<<<512,  256, 0, stream>>>(W_hh,  Whhb,  2048*512/8);
  conv_kernel<<<1024, 256, 0, stream>>>(W_dep, Wdepb, 8*512*512/8);

  leaf_mfma<<<4096, 256, 0, stream>>>(emb, Wihb, b_ih, b_hh, Z0);

  struct Lv { int node_base, child_base, mk, m; };
  const Lv LV[5] = {{585,4681,32768,4096},{73,585,4096,512},{9,73,512,64},{1,9,64,8},{0,1,8,1}};

  for (int l = 0; l < 5; ++l){
    const Lv lv = LV[l];
    const unsigned short* zin = (l % 2 == 0) ? Z0 : Z1;
    unsigned short*       zo  = (l % 2 == 0) ? Z1 : Z0;

    sort_kernel<<<1, 256, 0, stream>>>(dep, lv.child_base, lv.mk, perm, tile_p, meta);
    int maxtiles = (lv.mk + 63)/64 + 8;
    childx_mfma<<<maxtiles*8, 256, 0, stream>>>(zin, Wdepb, b_dep, perm, tile_p, meta, seq);

    int mbn = (lv.m + 63) / 64;
    for (int t = 0; t <= 8; ++t){
      int first = (t == 0), last = (t == 8);
      unsigned short* ho = (t % 2 == 0) ? hA : hB;
      const unsigned short* hi = (t % 2 == 0) ? hB : hA;
      const unsigned short* xb = (t < 8) ? (seq + (size_t)t*512) : nullptr;
      const float* xf = (t < 8) ? nullptr : (emb + (size_t)lv.node_base*512);
      long xs = (t < 8) ? 4096 : 512;
      step_mfma<<<mbn*32, 256, 0, stream>>>(xb, xf, xs, hi, ho, cbuf,
          Wihb, Whhb, b_ih, b_hh, lv.m, first, last,
          last ? (l < 4 ? zo : nullptr) : nullptr,
          (last && l == 4) ? out : nullptr);
    }
  }
}

// Round 3
// 1515.284 us; speedup vs baseline: 35.8519x; 1.7871x over previous
//
#include <hip/hip_runtime.h>

typedef __attribute__((ext_vector_type(8))) short short8;
typedef __attribute__((ext_vector_type(4))) float f32x4;

__device__ __forceinline__ unsigned short f2bf(float x){
  union { float f; unsigned u; } v; v.f = x;
  unsigned r = v.u + 0x7fffu + ((v.u >> 16) & 1u);
  return (unsigned short)(r >> 16);
}
__device__ __forceinline__ float sigm(float x){ return 1.0f / (1.0f + __expf(-x)); }
__device__ __forceinline__ float tanh_(float x){
  float e = __expf(2.0f * x);               // overflow -> inf -> 2/inf = 0 -> 1.0 (safe)
  return 1.0f - 2.0f / (e + 1.0f);
}
__device__ __forceinline__ short8 load_bf8_f32(const float* p){
  float4 a = *(const float4*)p;
  float4 b = *(const float4*)(p + 4);
  short8 r;
  r[0]=(short)f2bf(a.x); r[1]=(short)f2bf(a.y); r[2]=(short)f2bf(a.z); r[3]=(short)f2bf(a.w);
  r[4]=(short)f2bf(b.x); r[5]=(short)f2bf(b.y); r[6]=(short)f2bf(b.z); r[7]=(short)f2bf(b.w);
  return r;
}
__device__ __forceinline__ f32x4 mfma16(short8 a, short8 b, f32x4 c){
  return __builtin_amdgcn_mfma_f32_16x16x32_bf16(a, b, c, 0, 0, 0);
}
__device__ __forceinline__ void gload16(const void* g, void* lds){
  __builtin_amdgcn_global_load_lds((const __attribute__((address_space(1))) void*)g,
                                   (__attribute__((address_space(3))) void*)lds, 16, 0, 0);
}
__device__ __forceinline__ f32x4 shfl_xor4(f32x4 v, int m){
  f32x4 r;
  r[0]=__shfl_xor(v[0],m); r[1]=__shfl_xor(v[1],m);
  r[2]=__shfl_xor(v[2],m); r[3]=__shfl_xor(v[3],m);
  return r;
}
__device__ __forceinline__ float pick4(f32x4 v, int k){
  float a = (k&1)? v[1] : v[0];
  float b = (k&1)? v[3] : v[2];
  return (k&2)? b : a;
}
__device__ __forceinline__ f32x4 sel4(f32x4 a0, f32x4 a1, f32x4 a2, f32x4 a3, int k){
  f32x4 x = (k&1)? a1 : a0;
  f32x4 y = (k&1)? a3 : a2;
  return (k&2)? y : x;
}

// ---------------- fp32 -> bf16 plain convert (grid-stride) ----------------
__global__ __launch_bounds__(256) void conv_plain(const float* __restrict__ in,
                                                  unsigned short* __restrict__ out, int n8){
  for (int i = blockIdx.x*256 + threadIdx.x; i < n8; i += gridDim.x*256)
    *(short8*)(out + (size_t)i*8) = load_bf8_f32(in + (size_t)i*8);
}

// ---- 4-gate row interleave: dst row r=4j+g <- src row g*512+j, bf16 ----
__global__ __launch_bounds__(256) void remap4(const float* __restrict__ src,
                                              unsigned short* __restrict__ dst){
  int idx = blockIdx.x*256 + threadIdx.x;         // 2048*64 chunks
  int r = idx >> 6, c8 = idx & 63;
  int sr = (r & 3)*512 + (r >> 2);
  *(short8*)(dst + (size_t)r*512 + c8*8) = load_bf8_f32(src + (size_t)sr*512 + c8*8);
}
// ---- 2-gate (i,g) interleave for the leaf: dst row 2j+u <- src row (u?1024+j:j) ----
__global__ __launch_bounds__(256) void remap2(const float* __restrict__ src,
                                              unsigned short* __restrict__ dst){
  int idx = blockIdx.x*256 + threadIdx.x;         // 1024*64 chunks
  int r = idx >> 6, c8 = idx & 63;
  int sr = ((r & 1) ? 2 : 0)*512 + (r >> 1);
  *(short8*)(dst + (size_t)r*512 + c8*8) = load_bf8_f32(src + (size_t)sr*512 + c8*8);
}

// ---- transpose W_dep[p] (512x512 fp32) -> WdT[p] (bf16, [j][i]) ----
__global__ __launch_bounds__(256) void tr_wdep(const float* __restrict__ Wdep,
                                               unsigned short* __restrict__ WdT){
  __shared__ unsigned short tle[64][65];
  int bid = blockIdx.x; int p = bid >> 6; int tile = bid & 63;
  int i0 = (tile >> 3)*64, j0 = (tile & 7)*64;
  const float* src = Wdep + (size_t)p*512*512;
  for (int q = 0; q < 16; ++q){
    int e = q*256 + threadIdx.x;
    int li = e >> 6, lj = e & 63;
    tle[li][lj] = f2bf(src[(size_t)(i0+li)*512 + (j0+lj)]);
  }
  __syncthreads();
  unsigned short* dst = WdT + (size_t)p*512*512;
  for (int q = 0; q < 16; ++q){
    int e = q*256 + threadIdx.x;
    int lj = e >> 6, li = e & 63;
    dst[(size_t)(j0+lj)*512 + (i0+li)] = tle[li][lj];
  }
}

// ---- biases: bsum_il[4j+g] = b_ih[g*512+j]+b_hh[g*512+j] ----
__global__ __launch_bounds__(256) void bsum_k(const float* __restrict__ b_ih,
                                              const float* __restrict__ b_hh,
                                              float* __restrict__ bsum){
  int r = blockIdx.x*256 + threadIdx.x;
  if (r < 2048){ int g = r & 3, j = r >> 2; bsum[r] = b_ih[g*512+j] + b_hh[g*512+j]; }
}
// ---- bc_il[p][4j+g] = dot(W_ih[g*512+j], b_dep[p]) ----
__global__ __launch_bounds__(256) void bc_k(const float* __restrict__ W_ih,
                                            const float* __restrict__ b_dep,
                                            float* __restrict__ bc){
  __shared__ float bd[512];
  int p = blockIdx.x >> 3, ch = blockIdx.x & 7;
  for (int i = threadIdx.x; i < 512; i += 256) bd[i] = b_dep[p*512 + i];
  __syncthreads();
  int r = ch*256 + threadIdx.x;
  int g = r & 3, j = r >> 2;
  const float* wr = W_ih + (size_t)(g*512 + j)*512;
  float s = 0.0f;
  for (int i = 0; i < 512; ++i) s = fmaf(wr[i], bd[i], s);
  bc[(size_t)p*2048 + r] = s;
}

// ---- counting sort of nodes by child-dep-type for every (level, t) ----
__global__ __launch_bounds__(256) void sort_all(const int* __restrict__ dep,
                                                int* __restrict__ perm,
                                                int* __restrict__ tile_p,
                                                int* __restrict__ meta){
  const int l = blockIdx.x >> 3, t = blockIdx.x & 7;
  const int M_[5]  = {1,8,64,512,4096};
  const int CB_[5] = {1,9,73,585,4681};
  const int MT_[5] = {8,8,8,12,40};
  const int PB_[5] = {69632,61440,53248,40960,0};
  const int TB_[5] = {544,480,416,320,0};
  const int m = M_[l], cb = CB_[l], MT = MT_[l];
  int* pm = perm + PB_[l] + t*MT*128;
  int* tp = tile_p + TB_[l] + t*MT;
  __shared__ int cnt[8], base[8], fill[8];
  if (threadIdx.x < 8){ cnt[threadIdx.x] = 0; fill[threadIdx.x] = 0; }
  __syncthreads();
  for (int n = threadIdx.x; n < m; n += 256) atomicAdd(&cnt[dep[cb + n*8 + t]], 1);
  __syncthreads();
  if (threadIdx.x == 0){
    int tiles = 0;
    for (int p = 0; p < 8; ++p){
      base[p] = tiles*128;
      int g = (cnt[p] + 127) >> 7;
      for (int q = 0; q < g; ++q) tp[tiles + q] = p;
      tiles += g;
    }
    meta[l*8 + t] = tiles;
  }
  __syncthreads();
  for (int i = threadIdx.x; i < MT*128; i += 256) pm[i] = -1;
  __syncthreads();
  for (int n = threadIdx.x; n < m; n += 256){
    int p = dep[cb + n*8 + t];
    pm[base[p] + atomicAdd(&fill[p], 1)] = n;
  }
}

// ================= 128x128 MFMA GEMM kernels (m97 structure) =================
#define KLOOP_BODY(ABASE, BBASE)                                                     \
  for (int kt = 0; kt < 8; ++kt){                                                    \
    _Pragma("unroll")                                                                \
    for (int q = 0; q < 4; ++q){                                                     \
      gload16(ABASE[q] + kt*64, &As[(q*32 + w*8)*64]);                               \
      gload16(BBASE[q] + kt*64, &Bs[(q*32 + w*8)*64]);                               \
    }                                                                                \
    __syncthreads();                                                                 \
    _Pragma("unroll")                                                                \
    for (int kk = 0; kk < 2; ++kk){                                                  \
      short8 av[4], bv[4];                                                           \
      _Pragma("unroll")                                                              \
      for (int i = 0; i < 4; ++i) av[i] = *(const short8*)&As[(wm*64 + i*16 + r15)*64 + kk*32 + g4*8]; \
      _Pragma("unroll")                                                              \
      for (int i = 0; i < 4; ++i) bv[i] = *(const short8*)&Bs[(wn*64 + i*16 + r15)*64 + kk*32 + g4*8]; \
      _Pragma("unroll")                                                              \
      for (int i = 0; i < 4; ++i)                                                    \
        _Pragma("unroll")                                                            \
        for (int j = 0; j < 4; ++j) acc[i][j] = mfma16(av[i], bv[j], acc[i][j]);     \
    }                                                                                \
    __syncthreads();                                                                 \
  }

// ---- one-time: Wcombo_il[p] = Wih_il @ W_dep[p]  (C[r][j] = sum_i A[r][i]*WdT[p][j][i]) ----
__global__ __launch_bounds__(256) void combo_gemm(
    const unsigned short* __restrict__ A,      // Wih_il [2048][512]
    const unsigned short* __restrict__ WdT,    // [8][512][512]
    unsigned short* __restrict__ C)            // [8][2048][512]
{
  const int p  = blockIdx.x >> 6;
  const int mt = (blockIdx.x >> 2) & 15;
  const int nb = blockIdx.x & 3;
  __shared__ unsigned short As[128*64];
  __shared__ unsigned short Bs[128*64];
  const int tid = threadIdx.x, lane = tid & 63, w = tid >> 6;
  const int wm = w >> 1, wn = w & 1;
  const int r15 = lane & 15, g4 = lane >> 4;
  const int kc = (lane & 7)*8;

  const unsigned short* ab[4]; const unsigned short* bb[4];
  #pragma unroll
  for (int q = 0; q < 4; ++q){
    int rl = mt*128 + q*32 + w*8 + (lane >> 3);
    ab[q] = A + (size_t)rl*512 + kc;
    int br = nb*128 + q*32 + w*8 + (lane >> 3);
    bb[q] = WdT + (size_t)p*512*512 + (size_t)br*512 + kc;
  }
  f32x4 acc[4][4] = {};
  KLOOP_BODY(ab, bb)
  unsigned short* Cp = C + (size_t)p*2048*512;
  #pragma unroll
  for (int mi = 0; mi < 4; ++mi)
    #pragma unroll
    for (int ni = 0; ni < 4; ++ni)
      #pragma unroll
      for (int j = 0; j < 4; ++j){
        int row = mt*128 + wm*64 + mi*16 + g4*4 + j;
        int col = nb*128 + wn*64 + ni*16 + r15;
        Cp[(size_t)row*512 + col] = f2bf(acc[mi][ni][j]);
      }
}

// ---- leaf: z = sigm(emb@Wi^T+bi) * tanh(emb@Wg^T+bg), 2-gate interleaved B ----
__global__ __launch_bounds__(256) void leaf_gemm(
    const unsigned short* __restrict__ embL,   // embb + 4681*512
    const unsigned short* __restrict__ Wleaf,  // [1024][512] rows 2j+{0:i,1:g}
    const float* __restrict__ bsum,            // [2048] 4j+gate
    unsigned short* __restrict__ zo)           // [32768][512]
{
  const int nb = blockIdx.x & 7;
  const int mt = blockIdx.x >> 3;
  __shared__ unsigned short As[128*64];
  __shared__ unsigned short Bs[128*64];
  const int tid = threadIdx.x, lane = tid & 63, w = tid >> 6;
  const int wm = w >> 1, wn = w & 1;
  const int r15 = lane & 15, g4 = lane >> 4;
  const int kc = (lane & 7)*8;

  const unsigned short* ab[4]; const unsigned short* bb[4];
  #pragma unroll
  for (int q = 0; q < 4; ++q){
    int rl = mt*128 + q*32 + w*8 + (lane >> 3);
    ab[q] = embL + (size_t)rl*512 + kc;
    int br = nb*128 + q*32 + w*8 + (lane >> 3);
    bb[q] = Wleaf + (size_t)br*512 + kc;
  }
  f32x4 acc[4][4] = {};
  KLOOP_BODY(ab, bb)
  const int g2 = r15 & 1;
  #pragma unroll
  for (int ni = 0; ni < 4; ++ni){
    int ci = nb*128 + wn*64 + ni*16 + r15;
    float b = bsum[4*(ci >> 1) + (g2 ? 2 : 0)];
    #pragma unroll
    for (int mi = 0; mi < 4; ++mi){
      acc[mi][ni][0]+=b; acc[mi][ni][1]+=b; acc[mi][ni][2]+=b; acc[mi][ni][3]+=b;
    }
  }
  #pragma unroll
  for (int mi = 0; mi < 4; ++mi)
    #pragma unroll
    for (int ni = 0; ni < 4; ++ni){
      f32x4 a0 = acc[mi][ni];
      f32x4 a1 = shfl_xor4(a0, 1);
      f32x4 vi_ = g2 ? a1 : a0;
      f32x4 vg_ = g2 ? a0 : a1;
      int jz = (nb*128 + wn*64 + ni*16 + r15) >> 1;
      #pragma unroll
      for (int u = 0; u < 2; ++u){
        int jrow = (g2 << 1) + u;
        float zi = pick4(vi_, jrow), zg = pick4(vg_, jrow);
        int row = mt*128 + wm*64 + mi*16 + g4*4 + jrow;
        zo[(size_t)row*512 + jz] = f2bf(sigm(zi) * tanh_(zg));
      }
    }
}

// ---- recurrent step: gates = x@Bx^T + h@Whh^T + biases; fused LSTM pointwise ----
__global__ __launch_bounds__(256) void step_kernel(
    const unsigned short* __restrict__ zin,    // child z rows [*][512] (t<8)
    const unsigned short* __restrict__ embL,   // embb + node_base*512 (t==8)
    const unsigned short* __restrict__ Bx,     // Wcombo_il (t<8) / Wih_il (t==8)
    const unsigned short* __restrict__ Whh,    // Whh_il
    const int* __restrict__ perm,              // null => identity (t==8)
    const int* __restrict__ tile_p,            // null => p=0
    const int* __restrict__ meta,              // null => no check
    const float* __restrict__ bsum,
    const float* __restrict__ bcomb,           // bc_il (t<8) / null
    const unsigned short* __restrict__ hin,
    unsigned short* __restrict__ hout,
    float* __restrict__ cbuf,
    unsigned short* __restrict__ zout,         // last step, levels 4..1
    float* __restrict__ fout,                  // last step, level 0
    int m, int t, int first, int last)
{
  const int nb = blockIdx.x & 15;
  const int mt = blockIdx.x >> 4;
  if (meta && mt >= *meta) return;
  const int p = tile_p ? tile_p[mt] : 0;

  __shared__ unsigned short As[128*64];
  __shared__ unsigned short Bs[128*64];
  const int tid = threadIdx.x, lane = tid & 63, w = tid >> 6;
  const int wm = w >> 1, wn = w & 1;
  const int r15 = lane & 15, g4 = lane >> 4;
  const int kc = (lane & 7)*8;

  int nn[4];
  #pragma unroll
  for (int q = 0; q < 4; ++q){
    int rl = mt*128 + q*32 + w*8 + (lane >> 3);
    int n = perm ? perm[rl] : (rl < m ? rl : 0);
    nn[q] = (n < 0) ? 0 : n;
  }
  const unsigned short* BxP = Bx + (size_t)p*2048*512;

  f32x4 acc[4][4] = {};
  { // phase X
    const unsigned short* ab[4]; const unsigned short* bb[4];
    #pragma unroll
    for (int q = 0; q < 4; ++q){
      ab[q] = perm ? (zin + ((size_t)nn[q]*8 + t)*512 + kc)
                   : (embL + (size_t)nn[q]*512 + kc);
      int br = nb*128 + q*32 + w*8 + (lane >> 3);
      bb[q] = BxP + (size_t)br*512 + kc;
    }
    KLOOP_BODY(ab, bb)
  }
  if (!first){ // phase H
    const unsigned short* ab[4]; const unsigned short* bb[4];
    #pragma unroll
    for (int q = 0; q < 4; ++q){
      ab[q] = hin + (size_t)nn[q]*512 + kc;
      int br = nb*128 + q*32 + w*8 + (lane >> 3);
      bb[q] = Whh + (size_t)br*512 + kc;
    }
    KLOOP_BODY(ab, bb)
  }

  // biases (own gate), then quad-shfl to assemble all 4 gates per (row, zcol)
  const int gate = r15 & 3;
  #pragma unroll
  for (int ni = 0; ni < 4; ++ni){
    int ci = nb*128 + wn*64 + ni*16 + r15;
    float b = bsum[ci] + (bcomb ? bcomb[(size_t)p*2048 + ci] : 0.0f);
    #pragma unroll
    for (int mi = 0; mi < 4; ++mi){
      acc[mi][ni][0]+=b; acc[mi][ni][1]+=b; acc[mi][ni][2]+=b; acc[mi][ni][3]+=b;
    }
  }
  const int jr = r15 & 3;
  #pragma unroll
  for (int mi = 0; mi < 4; ++mi){
    int rl = mt*128 + wm*64 + mi*16 + g4*4 + jr;
    int n = perm ? perm[rl] : (rl < m ? rl : -1);
    #pragma unroll
    for (int ni = 0; ni < 4; ++ni){
      f32x4 a0 = acc[mi][ni];
      f32x4 a1 = shfl_xor4(a0, 1);
      f32x4 a2 = shfl_xor4(a0, 2);
      f32x4 a3 = shfl_xor4(a1, 2);
      f32x4 vi_ = sel4(a0,a1,a2,a3, gate);
      f32x4 vf_ = sel4(a0,a1,a2,a3, gate^1);
      f32x4 vg_ = sel4(a0,a1,a2,a3, gate^2);
      f32x4 vo_ = sel4(a0,a1,a2,a3, gate^3);
      float xi = pick4(vi_, jr), xf = pick4(vf_, jr);
      float xg = pick4(vg_, jr), xo = pick4(vo_, jr);
      if (n >= 0){
        int jz = nb*32 + wn*16 + ni*4 + (r15 >> 2);
        size_t idx = (size_t)n*512 + jz;
        float i_ = sigm(xi), f_ = sigm(xf), g_ = tanh_(xg), o_ = sigm(xo);
        float cold = first ? 0.0f : cbuf[idx];
        float cn = fmaf(f_, cold, i_*g_);
        if (!last){ cbuf[idx] = cn; hout[idx] = f2bf(o_*tanh_(cn)); }
        else { if (zout) zout[idx] = f2bf(cn); if (fout) fout[idx] = cn; }
      }
    }
  }
}

// OFF = {0, 1, 9, 73, 585, 4681, 37449}
extern "C" void kernel_launch(void* const* d_in, const int* in_sizes, int n_in,
                              void* d_out, int out_size, void* d_ws, size_t ws_size,
                              hipStream_t stream)
{
  (void)in_sizes; (void)n_in; (void)out_size; (void)ws_size;
  const float* emb   = (const float*)d_in[0];
  const int*   dep   = (const int*)  d_in[1];
  const float* W_dep = (const float*)d_in[2];
  const float* b_dep = (const float*)d_in[3];
  const float* W_ih  = (const float*)d_in[4];
  const float* W_hh  = (const float*)d_in[5];
  const float* b_ih  = (const float*)d_in[6];
  const float* b_hh  = (const float*)d_in[7];
  float* out = (float*)d_out;

  unsigned short* embb   = (unsigned short*)d_ws;                  // 37449*512
  unsigned short* Wih_il = embb   + 19173888ull;                   // 2048*512
  unsigned short* Whh_il = Wih_il + 1048576ull;                    // 2048*512
  unsigned short* Wleaf  = Whh_il + 1048576ull;                    // 1024*512
  unsigned short* WdT    = Wleaf  + 524288ull;                     // 8*512*512
  unsigned short* Wcombo = WdT    + 2097152ull;                    // 8*2048*512
  unsigned short* Z0     = Wcombo + 8388608ull;                    // 32768*512
  unsigned short* Z1     = Z0     + 16777216ull;                   // 4096*512
  unsigned short* hA     = Z1     + 2097152ull;                    // 4096*512
  unsigned short* hB     = hA     + 2097152ull;                    // 4096*512
  float* cbuf  = (float*)(hB + 2097152ull);                        // 4096*512 f32
  float* bsum  = cbuf + 2097152ull;                                // 2048
  float* bc    = bsum + 2048;                                      // 8*2048
  int*  perm   = (int*)(bc + 16384);                               // 77824
  int*  tile_p = perm + 77824;                                     // 608
  int*  meta   = tile_p + 608;                                     // 40

  conv_plain<<<2048, 256, 0, stream>>>(emb, embb, 2396736);
  remap4<<<512, 256, 0, stream>>>(W_ih, Wih_il);
  remap4<<<512, 256, 0, stream>>>(W_hh, Whh_il);
  remap2<<<256, 256, 0, stream>>>(W_ih, Wleaf);
  tr_wdep<<<512, 256, 0, stream>>>(W_dep, WdT);
  bsum_k<<<8, 256, 0, stream>>>(b_ih, b_hh, bsum);
  bc_k<<<64, 256, 0, stream>>>(W_ih, b_dep, bc);
  combo_gemm<<<512, 256, 0, stream>>>(Wih_il, WdT, Wcombo);
  sort_all<<<40, 256, 0, stream>>>(dep, perm, tile_p, meta);
  leaf_gemm<<<2048, 256, 0, stream>>>(embb + (size_t)4681*512, Wleaf, bsum, Z0);

  const int LM[5]  = {1, 8, 64, 512, 4096};
  const int LNB[5] = {0, 1, 9, 73, 585};
  const int LMT[5] = {8, 8, 8, 12, 40};
  const int LPB[5] = {69632, 61440, 53248, 40960, 0};
  const int LTB[5] = {544, 480, 416, 320, 0};

  int zi_idx = 0;  // Z0 holds leaf z
  unsigned short* zbufs[2] = {Z0, Z1};
  for (int l = 4; l >= 0; --l){
    unsigned short* zin = zbufs[zi_idx];
    unsigned short* zo  = zbufs[zi_idx ^ 1];
    int m = LM[l];
    for (int t = 0; t <= 8; ++t){
      int first = (t == 0), last = (t == 8);
      unsigned short* hi = (t & 1) ? hA : hB;
      unsigned short* ho = (t & 1) ? hB : hA;
      int grid = (t < 8) ? LMT[l]*16 : ((m + 127)/128)*16;
      step_kernel<<<grid, 256, 0, stream>>>(
          zin, embb + (size_t)LNB[l]*512,
          (t < 8) ? Wcombo : Wih_il, Whh_il,
          (t < 8) ? (perm + LPB[l] + t*LMT[l]*128) : nullptr,
          (t < 8) ? (tile_p + LTB[l] + t*LMT[l]) : nullptr,
          (t < 8) ? (meta + l*8 + t) : nullptr,
          bsum, (t < 8) ? bc : nullptr,
          hi, ho, cbuf,
          (last && l > 0) ? zo : nullptr,
          (last && l == 0) ? out : nullptr,
          m, t, first, last);
    }
    zi_idx ^= 1;
  }
}